// Round 7
// baseline (239.159 us; speedup 1.0000x reference)
//
#include <hip/hip_runtime.h>
#include <hip/hip_bf16.h>

#define BATCH   16384
#define NUM_IN  4096
#define NUM_OUT 1024
#define NNZ     262144
#define BN_EPS  1e-3f

typedef __attribute__((ext_vector_type(8)))  short short8;
typedef __attribute__((ext_vector_type(4)))  float f32x4;
typedef __attribute__((ext_vector_type(4)))  unsigned int u32x4;

typedef __attribute__((address_space(3))) void        lds_void_t;
typedef const __attribute__((address_space(1))) void  g_void_t;

__device__ inline unsigned short f2bf(float f) {
    unsigned int u = __builtin_bit_cast(unsigned int, f);
    u += 0x7fffu + ((u >> 16) & 1u);
    return (unsigned short)(u >> 16);
}

// ---------------- kernel 1: zero W_t (fp32, transposed [NUM_OUT][NUM_IN]) ----
__global__ void k_zero(f32x4* __restrict__ p) {
    p[(size_t)blockIdx.x * 256 + threadIdx.x] = f32x4{0.f, 0.f, 0.f, 0.f};
}

// ---------------- kernel 2: scatter-add sparse values into W_t --------------
__global__ void k_scatter(const float* __restrict__ v, const int* __restrict__ r,
                          const int* __restrict__ c, float* __restrict__ wtf) {
    int i = blockIdx.x * 256 + threadIdx.x;
    atomicAdd(&wtf[(size_t)c[i] * NUM_IN + r[i]], v[i]);
}

// ---------------- kernel 3: fold BN scale into W (bf16) + bias_out ----------
__global__ void k_wprep(const float* __restrict__ wtf, const float* __restrict__ gamma,
                        const float* __restrict__ beta, const float* __restrict__ mean,
                        const float* __restrict__ var, unsigned short* __restrict__ wtb,
                        float* __restrict__ bias) {
    const int n = blockIdx.x;
    const int t = threadIdx.x;
    float acc = 0.f;
    for (int k = t; k < NUM_IN; k += 256) {
        float w = wtf[(size_t)n * NUM_IN + k];
        float s = gamma[k] * rsqrtf(var[k] + BN_EPS);
        wtb[(size_t)n * NUM_IN + k] = f2bf(w * s);
        acc += (beta[k] - mean[k] * s) * w;
    }
    #pragma unroll
    for (int o = 32; o; o >>= 1) acc += __shfl_down(acc, o, 64);
    __shared__ float red[4];
    if ((t & 63) == 0) red[t >> 6] = acc;
    __syncthreads();
    if (t == 0) bias[n] = red[0] + red[1] + red[2] + red[3];
}

// ---------------- kernel 4: bf16 MFMA GEMM: out = x @ W'^T + bias -----------
// BM=BN=256, BK=32. 512 thr = 8 waves (4M x 2N), per-wave 64x128, 16x16x32.
// FRAGMENT-MAJOR LDS: A as [h=2][mf=16][lane=64]x16B (fp32), B as
// [nf=16][lane=64]x16B (bf16). Every ds_read is base + frag*1024 + lane*16 —
// linear in lane => ZERO bank conflicts; frag index folds to imm offset.
// The permutation lives in the global_load_lds SOURCE address (linear dest).
// Ring-3 slots (48 KB each, 144 KiB), ONE counted vmcnt(6)/K-tile, 2 barriers/
// K-tile (ph0 stages A-region of kt+2, ph1 stages B-region: slot/region
// disjointness makes drift<=1 phase race-free).
#define BM 256
#define BN 256
#define BK 32
#define NT (NUM_IN / BK)      /* 128 */
#define PSLOT 49152           /* A 32 KB + B 16 KB */
#define BOFF 32768

__global__ __launch_bounds__(512, 2) void k_gemm(const float* __restrict__ x,
                                                 const unsigned short* __restrict__ wt,
                                                 const float* __restrict__ bias,
                                                 float* __restrict__ out) {
    __shared__ __align__(128) char lds[3 * PSLOT];   // 144 KiB

    // XCD swizzle: 256 blocks (1/CU); XCD x gets 8 m-panels x all 4 n-tiles.
    const int bid = blockIdx.x;
    const int swz = (bid & 7) * 32 + (bid >> 3);
    const int m0 = (swz >> 2) * BM;
    const int n0 = (swz & 3) * BN;

    const int t    = threadIdx.x;
    const int lane = t & 63;
    const int wid  = t >> 6;
    const int wm   = wid >> 1;        // 0..3 -> 64-row strip
    const int wn   = wid & 1;         // 0..1 -> 128-col strip

    const char* xb = (const char*)x;
    const char* wb = (const char*)wt;

    // A staging -> [h][mf][lane]: issue i: h=i>>1, mf=(i&1)*8+(t>>6), l=t&63.
    // source: row = m0 + mf*16 + (l&15), kbyte = (l>>4&3)*32 + h*16
    auto stageA = [&](int kt, int sl) {
        #pragma unroll
        for (int i = 0; i < 4; ++i) {
            int row = m0 + ((i & 1) * 8 + (t >> 6)) * 16 + (t & 15);
            size_t src = (size_t)row * (NUM_IN * 4) + (size_t)kt * (BK * 4)
                       + ((t >> 4) & 3) * 32 + (i >> 1) * 16;
            __builtin_amdgcn_global_load_lds((g_void_t*)(xb + src),
                (lds_void_t*)(lds + sl * PSLOT + i * 8192 + t * 16), 16, 0, 0);
        }
    };
    // B staging -> [nf][lane]: issue i: nf = i*8+(t>>6), l=t&63.
    // source: col = n0 + nf*16 + (l&15), kbyte = (l>>4&3)*16
    auto stageB = [&](int kt, int sl) {
        #pragma unroll
        for (int i = 0; i < 2; ++i) {
            int col = n0 + (i * 8 + (t >> 6)) * 16 + (t & 15);
            size_t src = (size_t)col * (NUM_IN * 2) + (size_t)kt * (BK * 2)
                       + ((t >> 4) & 3) * 16;
            __builtin_amdgcn_global_load_lds((g_void_t*)(wb + src),
                (lds_void_t*)(lds + sl * PSLOT + BOFF + i * 8192 + t * 16), 16, 0, 0);
        }
    };

    f32x4 alo[4], ahi[4];
    short8 af[4], bf0[4], bf1[4];
    f32x4 acc[4][8] = {};

    auto convA = [&]() {
        #pragma unroll
        for (int m = 0; m < 4; ++m) {
            const unsigned int* f0 = (const unsigned int*)&alo[m];
            const unsigned int* f1 = (const unsigned int*)&ahi[m];
            u32x4 p;   // fp32 -> bf16 (RTZ), 1 v_perm per 2 elems
            p[0] = __builtin_amdgcn_perm(f0[1], f0[0], 0x07060302u);
            p[1] = __builtin_amdgcn_perm(f0[3], f0[2], 0x07060302u);
            p[2] = __builtin_amdgcn_perm(f1[1], f1[0], 0x07060302u);
            p[3] = __builtin_amdgcn_perm(f1[3], f1[2], 0x07060302u);
            af[m] = __builtin_bit_cast(short8, p);
        }
    };

    // prologue: stage tiles 0,1 fully; wait tile 0 (tile 1's 6 in flight)
    stageA(0, 0); stageB(0, 0);
    stageA(1, 1); stageB(1, 1);
    asm volatile("s_waitcnt vmcnt(6)" ::: "memory");
    __builtin_amdgcn_s_barrier();

    int cur = 0, s2 = 2;
    #pragma unroll 1
    for (int kt = 0; kt < NT; ++kt) {
        const bool st = (kt + 2) < NT;
        const char* A = lds + cur * PSLOT + (wm * 4) * 1024 + lane * 16;
        const char* B = lds + cur * PSLOT + BOFF + (wn * 8) * 1024 + lane * 16;
        // ---- phase 0: A-frags + B n-half0; stage A-region of kt+2 ----
        if (st) stageA(kt + 2, s2);
        #pragma unroll
        for (int m = 0; m < 4; ++m) {
            alo[m] = *(const f32x4*)(A + m * 1024);
            ahi[m] = *(const f32x4*)(A + m * 1024 + 16384);
        }
        #pragma unroll
        for (int n = 0; n < 4; ++n)
            bf0[n] = *(const short8*)(B + n * 1024);
        __builtin_amdgcn_s_barrier();
        asm volatile("s_waitcnt lgkmcnt(0)" ::: "memory");
        __builtin_amdgcn_sched_barrier(0);
        convA();
        __builtin_amdgcn_s_setprio(1);
        #pragma unroll
        for (int m = 0; m < 4; ++m)
            #pragma unroll
            for (int n = 0; n < 4; ++n)
                acc[m][n] = __builtin_amdgcn_mfma_f32_16x16x32_bf16(
                    af[m], bf0[n], acc[m][n], 0, 0, 0);
        __builtin_amdgcn_s_setprio(0);
        // ---- phase 1: B n-half1; stage B-region of kt+2 ----
        if (st) stageB(kt + 2, s2);
        #pragma unroll
        for (int n = 0; n < 4; ++n)
            bf1[n] = *(const short8*)(B + (4 + n) * 1024);
        if (st)                asm volatile("s_waitcnt vmcnt(6)" ::: "memory");
        else if (kt + 1 < NT)  asm volatile("s_waitcnt vmcnt(0)" ::: "memory");
        __builtin_amdgcn_s_barrier();
        asm volatile("s_waitcnt lgkmcnt(0)" ::: "memory");
        __builtin_amdgcn_sched_barrier(0);
        __builtin_amdgcn_s_setprio(1);
        #pragma unroll
        for (int m = 0; m < 4; ++m)
            #pragma unroll
            for (int n = 0; n < 4; ++n)
                acc[m][n + 4] = __builtin_amdgcn_mfma_f32_16x16x32_bf16(
                    af[m], bf1[n], acc[m][n + 4], 0, 0, 0);
        __builtin_amdgcn_s_setprio(0);
        cur = (cur < 2) ? cur + 1 : 0;
        s2  = (s2 < 2) ? s2 + 1 : 0;
    }

    // epilogue: D frag mapping col=lane&15, row=(lane>>4)*4+r
    float bj[8];
    #pragma unroll
    for (int n = 0; n < 8; ++n) bj[n] = bias[n0 + wn * 128 + n * 16 + (lane & 15)];
    const int mb = m0 + wm * 64 + (lane >> 4) * 4;
    const int nb = n0 + wn * 128 + (lane & 15);
    #pragma unroll
    for (int m = 0; m < 4; ++m)
        #pragma unroll
        for (int n = 0; n < 8; ++n)
            #pragma unroll
            for (int r = 0; r < 4; ++r)
                out[(size_t)(mb + m * 16 + r) * NUM_OUT + (nb + n * 16)] =
                    acc[m][n][r] + bj[n];
}

extern "C" void kernel_launch(void* const* d_in, const int* in_sizes, int n_in,
                              void* d_out, int out_size, void* d_ws, size_t ws_size,
                              hipStream_t stream) {
    const float* x     = (const float*)d_in[0];
    const float* spv   = (const float*)d_in[1];
    const float* gamma = (const float*)d_in[2];
    const float* beta  = (const float*)d_in[3];
    const float* mean  = (const float*)d_in[4];
    const float* var   = (const float*)d_in[5];
    const int*   rows  = (const int*)d_in[6];
    const int*   cols  = (const int*)d_in[7];
    float* out = (float*)d_out;

    // W_t fp32 scratch lives in d_out (dead before k_gemm overwrites it).
    float* wtf = (float*)d_out;
    unsigned short* wtb = (unsigned short*)d_ws;
    float* bias = (float*)((char*)d_ws + (size_t)NUM_IN * NUM_OUT * sizeof(unsigned short));

    hipLaunchKernelGGL(k_zero, dim3((NUM_IN * NUM_OUT / 4) / 256), dim3(256), 0, stream,
                       (f32x4*)wtf);
    hipLaunchKernelGGL(k_scatter, dim3(NNZ / 256), dim3(256), 0, stream,
                       spv, rows, cols, wtf);
    hipLaunchKernelGGL(k_wprep, dim3(NUM_OUT), dim3(256), 0, stream,
                       wtf, gamma, beta, mean, var, wtb, bias);
    hipLaunchKernelGGL(k_gemm, dim3((BATCH / BM) * (NUM_OUT / BN)), dim3(512), 0, stream,
                       x, wtb, bias, out);
}

// Round 8
// 218.081 us; speedup vs baseline: 1.0967x; 1.0967x over previous
//
#include <hip/hip_runtime.h>
#include <hip/hip_bf16.h>

#define BATCH   16384
#define NUM_IN  4096
#define NUM_OUT 1024
#define NNZ     262144
#define BN_EPS  1e-3f

typedef __attribute__((ext_vector_type(8)))  short short8;
typedef __attribute__((ext_vector_type(4)))  float f32x4;
typedef __attribute__((ext_vector_type(2)))  unsigned int u32x2;

typedef __attribute__((address_space(3))) void        lds_void_t;
typedef const __attribute__((address_space(1))) void  g_void_t;

__device__ inline unsigned short f2bf(float f) {
    unsigned int u = __builtin_bit_cast(unsigned int, f);
    u += 0x7fffu + ((u >> 16) & 1u);
    return (unsigned short)(u >> 16);
}

// ---------------- kernel 1: zero W_t (fp32, transposed [NUM_OUT][NUM_IN]) ----
__global__ void k_zero(f32x4* __restrict__ p) {
    p[(size_t)blockIdx.x * 256 + threadIdx.x] = f32x4{0.f, 0.f, 0.f, 0.f};
}

// ---------------- kernel 2: scatter-add sparse values into W_t --------------
__global__ void k_scatter(const float* __restrict__ v, const int* __restrict__ r,
                          const int* __restrict__ c, float* __restrict__ wtf) {
    int i = blockIdx.x * 256 + threadIdx.x;
    atomicAdd(&wtf[(size_t)c[i] * NUM_IN + r[i]], v[i]);
}

// ---------------- kernel 3: fold BN scale into W (bf16) + bias_out ----------
__global__ void k_wprep(const float* __restrict__ wtf, const float* __restrict__ gamma,
                        const float* __restrict__ beta, const float* __restrict__ mean,
                        const float* __restrict__ var, unsigned short* __restrict__ wtb,
                        float* __restrict__ bias) {
    const int n = blockIdx.x;
    const int t = threadIdx.x;
    float acc = 0.f;
    for (int k = t; k < NUM_IN; k += 256) {
        float w = wtf[(size_t)n * NUM_IN + k];
        float s = gamma[k] * rsqrtf(var[k] + BN_EPS);
        wtb[(size_t)n * NUM_IN + k] = f2bf(w * s);
        acc += (beta[k] - mean[k] * s) * w;
    }
    #pragma unroll
    for (int o = 32; o; o >>= 1) acc += __shfl_down(acc, o, 64);
    __shared__ float red[4];
    if ((t & 63) == 0) red[t >> 6] = acc;
    __syncthreads();
    if (t == 0) bias[n] = red[0] + red[1] + red[2] + red[3];
}

// ---------------- kernel 4: bf16 MFMA GEMM: out = x @ W'^T + bias -----------
// BM=BN=256, BK=64, 512 thr = 8 waves (2M x 4N), per-wave 128x64, 16x16x32.
// A: reg-staged fp32 (flat 256-B-segment coalesced loads, issued ph0) ->
//    v_perm bf16 -> conflict-free ds_write_b64 at ph3 (3-phase latency gap)
//    into FRAGMENT-MAJOR layout [h][mf][chunk(l)] (bijective -> uniform banks).
// B: global_load_lds (coalesced 128-B-window pre-swizzled source), issued ph3
//    for tile kt+2 -> 4 loads stay in flight across barriers (T4).
// 4 phases/iter, each {issue | 4-8 ds_read | sbar | lgkm(0) | 16 MFMA | sbar};
// ONE counted vmcnt(4) per iter. Double-buffered 128 KiB LDS.
#define BM 256
#define BN 256
#define BK 64
#define NT (NUM_IN / BK)      /* 64 */
#define SLOT 65536            /* A 32 KB (bf16 frag-major) + B 32 KB */
#define BOFF 32768

__global__ __launch_bounds__(512, 2) void k_gemm(const float* __restrict__ x,
                                                 const unsigned short* __restrict__ wt,
                                                 const float* __restrict__ bias,
                                                 float* __restrict__ out) {
    __shared__ __align__(128) char lds[2 * SLOT];

    // XCD swizzle: 256 blocks (1/CU); XCD x gets 8 m-panels x all 4 n-tiles.
    const int bid = blockIdx.x;
    const int swz = (bid & 7) * 32 + (bid >> 3);
    const int m0 = (swz >> 2) * BM;
    const int n0 = (swz & 3) * BN;

    const int t    = threadIdx.x;
    const int lane = t & 63;
    const int wid  = t >> 6;
    const int wm   = wid >> 2;        // 0..1 -> 128-row strip
    const int wn   = wid & 3;         // 0..3 -> 64-col strip

    const char* xb = (const char*)x;
    const char* wb = (const char*)wt;

    // A-read: frag (h, mf): lane l -> chunk ((l&15)<<2)|(l>>4)  (dense/uniform)
    const int cpo   = ((((lane & 15) << 2) | (lane >> 4)) * 16);
    const int aRdW  = wm * 8192;      // wave's mf base (8 mf x 1 KB)
    // B-read: col = wn*64+nf*16+(l&15); chunk = (h*4+(l>>4)) ^ (l&7)  (uniform)
    const int bColB = (wn * 64 + (lane & 15)) * 128;
    const int bC0   = (((lane >> 4)    ) ^ (lane & 7)) * 16;
    const int bC1   = ((4 + (lane >> 4)) ^ (lane & 7)) * 16;
    // A-write: thread t issue i: row=i*32+(t>>4), k-fp32=(t&15)*4 ->
    //   h=(t>>3)&1, mf=2i+(t>>8), chunk=((t>>4)&15)*4+((t>>1)&3), half=t&1
    const int awBase = ((t >> 3) & 1) * 16384 + (t >> 8) * 1024
                     + ((((t >> 4) & 15) * 4 + ((t >> 1) & 3)) * 16) + (t & 1) * 8;

    f32x4 rA[8];
    auto loadA = [&](int kt) {      // 8x dwordx4, 16 lanes dense per 256-B row
        #pragma unroll
        for (int i = 0; i < 8; ++i)
            rA[i] = *(const f32x4*)(xb
                + (size_t)(m0 + i * 32 + (t >> 4)) * (NUM_IN * 4)
                + (size_t)kt * (BK * 4) + (t & 15) * 16);
    };
    auto convWriteA = [&](int sl) {
        char* dst = lds + sl * SLOT + awBase;
        #pragma unroll
        for (int i = 0; i < 8; ++i) {
            const unsigned int* f = (const unsigned int*)&rA[i];
            u32x2 w;
            w.x = __builtin_amdgcn_perm(f[1], f[0], 0x07060302u);
            w.y = __builtin_amdgcn_perm(f[3], f[2], 0x07060302u);
            *(u32x2*)(dst + i * 2048) = w;
        }
    };
    auto stageB = [&](int kt, int sl) {   // 4x 8KB, 8 lanes/128-B window
        #pragma unroll
        for (int i = 0; i < 4; ++i) {
            int col = i * 64 + (t >> 3);
            size_t src = (size_t)(n0 + col) * (NUM_IN * 2) + (size_t)kt * (BK * 2)
                       + (((t & 7) ^ ((t >> 3) & 7)) * 16);
            __builtin_amdgcn_global_load_lds((g_void_t*)(wb + src),
                (lds_void_t*)(lds + sl * SLOT + BOFF + i * 8192 + t * 16), 16, 0, 0);
        }
    };

    short8 af[4], bf0[4], bf1[4];
    auto readA4 = [&](const char* A, int h, int mh) {
        const char* base = A + h * 16384 + aRdW + mh * 4096 + cpo;
        af[0] = *(const short8*)(base);
        af[1] = *(const short8*)(base + 1024);
        af[2] = *(const short8*)(base + 2048);
        af[3] = *(const short8*)(base + 3072);
    };
    auto readB4 = [&](const char* B, int co, short8* bf) {
        const char* base = B + bColB + co;
        bf[0] = *(const short8*)(base);
        bf[1] = *(const short8*)(base + 2048);
        bf[2] = *(const short8*)(base + 4096);
        bf[3] = *(const short8*)(base + 6144);
    };

    f32x4 acc[8][4] = {};
    auto mfma16 = [&](short8* bf, int mlb) {
        __builtin_amdgcn_s_setprio(1);
        #pragma unroll
        for (int mi = 0; mi < 4; ++mi)
            #pragma unroll
            for (int nf = 0; nf < 4; ++nf)
                acc[mlb + mi][nf] = __builtin_amdgcn_mfma_f32_16x16x32_bf16(
                    af[mi], bf[nf], acc[mlb + mi][nf], 0, 0, 0);
        __builtin_amdgcn_s_setprio(0);
    };

    // ---- prologue: A(0) direct; B(0),B(1) DMA; B(1) stays in flight ----
    loadA(0);                                     // vm +8
    stageB(0, 0);                                 // vm +4
    stageB(1, 1);                                 // vm +4
    asm volatile("s_waitcnt vmcnt(8)" ::: "memory");   // A(0) done
    convWriteA(0);
    asm volatile("s_waitcnt vmcnt(4)" ::: "memory");   // B(0) done, B(1) flies
    asm volatile("s_waitcnt lgkmcnt(0)" ::: "memory");
    __builtin_amdgcn_s_barrier();

    #pragma unroll 1
    for (int kt = 0; kt < NT; ++kt) {
        const int s = kt & 1;
        const char* Ap = lds + s * SLOT;
        const char* Bp = Ap + BOFF;
        const bool st1 = (kt + 1) < NT;
        const bool st2 = (kt + 2) < NT;
        // ---- phase 0: (h0, mh0) ----
        if (st1) loadA(kt + 1);
        readB4(Bp, bC0, bf0);
        readA4(Ap, 0, 0);
        __builtin_amdgcn_s_barrier();
        asm volatile("s_waitcnt lgkmcnt(0)" ::: "memory");
        __builtin_amdgcn_sched_barrier(0);
        mfma16(bf0, 0);
        __builtin_amdgcn_s_barrier();
        // ---- phase 1: (h0, mh1) ----
        readA4(Ap, 0, 1);
        __builtin_amdgcn_s_barrier();
        asm volatile("s_waitcnt lgkmcnt(0)" ::: "memory");
        __builtin_amdgcn_sched_barrier(0);
        mfma16(bf0, 4);
        __builtin_amdgcn_s_barrier();
        // ---- phase 2: (h1, mh0) ----
        readB4(Bp, bC1, bf1);
        readA4(Ap, 1, 0);
        __builtin_amdgcn_s_barrier();
        asm volatile("s_waitcnt lgkmcnt(0)" ::: "memory");
        __builtin_amdgcn_sched_barrier(0);
        mfma16(bf1, 0);
        __builtin_amdgcn_s_barrier();
        // ---- phase 3: (h1, mh1) + stage B(kt+2) + convert/write A(kt+1) ----
        if (st2) stageB(kt + 2, s);       // slot s's B: its last read was ph2
        readA4(Ap, 1, 1);
        if (st1) {
            if (st2) asm volatile("s_waitcnt vmcnt(4)" ::: "memory");
            else     asm volatile("s_waitcnt vmcnt(0)" ::: "memory");
            convWriteA(s ^ 1);            // A(kt+1) -> other slot
        }
        __builtin_amdgcn_s_barrier();
        asm volatile("s_waitcnt lgkmcnt(0)" ::: "memory");
        __builtin_amdgcn_sched_barrier(0);
        mfma16(bf1, 4);
        __builtin_amdgcn_s_barrier();
    }

    // epilogue: D frag mapping col=lane&15, row=(lane>>4)*4+r
    float bj[4];
    #pragma unroll
    for (int n = 0; n < 4; ++n) bj[n] = bias[n0 + wn * 64 + n * 16 + (lane & 15)];
    const int mb = m0 + wm * 128 + (lane >> 4) * 4;
    const int nb = n0 + wn * 64 + (lane & 15);
    #pragma unroll
    for (int ml = 0; ml < 8; ++ml)
        #pragma unroll
        for (int n = 0; n < 4; ++n)
            #pragma unroll
            for (int r = 0; r < 4; ++r)
                out[(size_t)(mb + ml * 16 + r) * NUM_OUT + (nb + n * 16)] =
                    acc[ml][n][r] + bj[n];
}

extern "C" void kernel_launch(void* const* d_in, const int* in_sizes, int n_in,
                              void* d_out, int out_size, void* d_ws, size_t ws_size,
                              hipStream_t stream) {
    const float* x     = (const float*)d_in[0];
    const float* spv   = (const float*)d_in[1];
    const float* gamma = (const float*)d_in[2];
    const float* beta  = (const float*)d_in[3];
    const float* mean  = (const float*)d_in[4];
    const float* var   = (const float*)d_in[5];
    const int*   rows  = (const int*)d_in[6];
    const int*   cols  = (const int*)d_in[7];
    float* out = (float*)d_out;

    // W_t fp32 scratch lives in d_out (dead before k_gemm overwrites it).
    float* wtf = (float*)d_out;
    unsigned short* wtb = (unsigned short*)d_ws;
    float* bias = (float*)((char*)d_ws + (size_t)NUM_IN * NUM_OUT * sizeof(unsigned short));

    hipLaunchKernelGGL(k_zero, dim3((NUM_IN * NUM_OUT / 4) / 256), dim3(256), 0, stream,
                       (f32x4*)wtf);
    hipLaunchKernelGGL(k_scatter, dim3(NNZ / 256), dim3(256), 0, stream,
                       spv, rows, cols, wtf);
    hipLaunchKernelGGL(k_wprep, dim3(NUM_OUT), dim3(256), 0, stream,
                       wtf, gamma, beta, mean, var, wtb, bias);
    hipLaunchKernelGGL(k_gemm, dim3((BATCH / BM) * (NUM_OUT / BN)), dim3(512), 0, stream,
                       x, wtb, bias, out);
}

// Round 9
// 214.282 us; speedup vs baseline: 1.1161x; 1.0177x over previous
//
#include <hip/hip_runtime.h>
#include <hip/hip_bf16.h>

#define BATCH   16384
#define NUM_IN  4096
#define NUM_OUT 1024
#define NNZ     262144
#define BN_EPS  1e-3f

typedef __attribute__((ext_vector_type(8)))  short short8;
typedef __attribute__((ext_vector_type(4)))  float f32x4;
typedef __attribute__((ext_vector_type(4)))  unsigned int u32x4;

typedef __attribute__((address_space(3))) void        lds_void_t;
typedef const __attribute__((address_space(1))) void  g_void_t;

__device__ inline unsigned short f2bf(float f) {
    unsigned int u = __builtin_bit_cast(unsigned int, f);
    u += 0x7fffu + ((u >> 16) & 1u);
    return (unsigned short)(u >> 16);
}

// ---------------- kernel 1: zero W_t (fp32, transposed [NUM_OUT][NUM_IN]) ----
__global__ void k_zero(f32x4* __restrict__ p) {
    p[(size_t)blockIdx.x * 256 + threadIdx.x] = f32x4{0.f, 0.f, 0.f, 0.f};
}

// ---------------- kernel 2: scatter-add sparse values into W_t --------------
__global__ void k_scatter(const float* __restrict__ v, const int* __restrict__ r,
                          const int* __restrict__ c, float* __restrict__ wtf) {
    int i = blockIdx.x * 256 + threadIdx.x;
    atomicAdd(&wtf[(size_t)c[i] * NUM_IN + r[i]], v[i]);
}

// ---------------- kernel 3: fold BN scale into W (bf16) + bias_out ----------
__global__ void k_wprep(const float* __restrict__ wtf, const float* __restrict__ gamma,
                        const float* __restrict__ beta, const float* __restrict__ mean,
                        const float* __restrict__ var, unsigned short* __restrict__ wtb,
                        float* __restrict__ bias) {
    const int n = blockIdx.x;
    const int t = threadIdx.x;
    float acc = 0.f;
    for (int k = t; k < NUM_IN; k += 256) {
        float w = wtf[(size_t)n * NUM_IN + k];
        float s = gamma[k] * rsqrtf(var[k] + BN_EPS);
        wtb[(size_t)n * NUM_IN + k] = f2bf(w * s);
        acc += (beta[k] - mean[k] * s) * w;
    }
    #pragma unroll
    for (int o = 32; o; o >>= 1) acc += __shfl_down(acc, o, 64);
    __shared__ float red[4];
    if ((t & 63) == 0) red[t >> 6] = acc;
    __syncthreads();
    if (t == 0) bias[n] = red[0] + red[1] + red[2] + red[3];
}

// ---------------- kernel 4: bf16 MFMA GEMM: out = x @ W'^T + bias -----------
// BM=BN=256, BK=64, 512 thr = 8 waves (2M x 4N), per-wave 128x64, 16x16x32.
// A: reg-staged fp32 (8 thr per 256-B row, dense) -> v_perm bf16 -> one
//    ds_write_b128/chunk into FRAG-MAJOR [kk][mf][lam'] with
//    lam' = lam ^ ((lam>>4)|(kk<<2))  (write banks uniform, read = permuted
//    linear => conflict-free, bijective).
// B: global_load_lds, source pre-XORed inside its 128-B window; read chunk
//    (kk*4+(l>>4)) ^ (l&7)  (2-way = free).
// 4 phases/K-tile: {issues | ds_reads | sbar | lgkm(0) | 16 MFMA | sbar};
// ONE counted vmcnt(4)/K-tile (B-DMA of kt+2 stays in flight). 128 KiB LDS.
#define BM 256
#define BN 256
#define BK 64
#define NT (NUM_IN / BK)      /* 64 */
#define SLOT 65536            /* A 32 KB (bf16 frag-major) + B 32 KB */
#define BOFF 32768

__global__ __launch_bounds__(512, 2) void k_gemm(const float* __restrict__ x,
                                                 const unsigned short* __restrict__ wt,
                                                 const float* __restrict__ bias,
                                                 float* __restrict__ out) {
    __shared__ __align__(128) char lds[2 * SLOT];

    // XCD swizzle: 256 blocks (1/CU); XCD x gets 8 m-panels x all 4 n-tiles.
    const int bid = blockIdx.x;
    const int swz = (bid & 7) * 32 + (bid >> 3);
    const int m0 = (swz >> 2) * BM;
    const int n0 = (swz & 3) * BN;

    const int t    = threadIdx.x;
    const int lane = t & 63;
    const int wid  = t >> 6;
    const int wm   = wid >> 2;        // 0..1 -> 128-row strip
    const int wn   = wid & 3;         // 0..3 -> 64-col strip

    const char* xb = (const char*)x;
    const char* wb = (const char*)wt;

    // A-write: thread t, issue i: row = i*64+(t>>3), ks = (t&7)*8..+7
    //   kk=(t>>2)&1, mf=i*4+(t>>7), lam=((t>>3)&15)|((t&3)<<4), lam'=lam^(t&7)
    const int awBase = ((t >> 2) & 1) * 16384 + (t >> 7) * 1024
                     + (((((t >> 3) & 15) | ((t & 3) << 4)) ^ (t & 7)) * 16);
    // A-read lane offsets per kk: lam' = lane ^ ((lane>>4)|(kk<<2))
    const int la0 = (lane ^ (lane >> 4)) * 16;
    const int la1 = (lane ^ ((lane >> 4) | 4)) * 16;
    // B-read: col = wn*64+nf*16+(l&15); chunk = (kk*4+(l>>4)) ^ (l&7)
    const int bColB = (wn * 64 + (lane & 15)) * 128;
    const int bC0   = (((lane >> 4)    ) ^ (lane & 7)) * 16;
    const int bC1   = ((4 + (lane >> 4)) ^ (lane & 7)) * 16;

    f32x4 rA[8];
    auto loadA = [&](int kt) {      // 8 thr per 256-B row, fully dense
        #pragma unroll
        for (int i = 0; i < 4; ++i) {
            const char* p = xb + (size_t)(m0 + i * 64 + (t >> 3)) * (NUM_IN * 4)
                          + (size_t)kt * (BK * 4) + (t & 7) * 32;
            rA[2 * i]     = *(const f32x4*)(p);
            rA[2 * i + 1] = *(const f32x4*)(p + 16);
        }
    };
    auto convWriteA = [&](int sl) {
        char* dst = lds + sl * SLOT + awBase;
        #pragma unroll
        for (int i = 0; i < 4; ++i) {
            const unsigned int* f0 = (const unsigned int*)&rA[2 * i];
            const unsigned int* f1 = (const unsigned int*)&rA[2 * i + 1];
            u32x4 w;   // 8 fp32 -> 8 bf16 (RTZ), k-ascending
            w[0] = __builtin_amdgcn_perm(f0[1], f0[0], 0x07060302u);
            w[1] = __builtin_amdgcn_perm(f0[3], f0[2], 0x07060302u);
            w[2] = __builtin_amdgcn_perm(f1[1], f1[0], 0x07060302u);
            w[3] = __builtin_amdgcn_perm(f1[3], f1[2], 0x07060302u);
            *(u32x4*)(dst + i * 4096) = w;   // mf advances by 4 per issue
        }
    };
    auto stageB = [&](int kt, int sl) {   // 4x 8KB, 8 lanes/128-B window
        #pragma unroll
        for (int i = 0; i < 4; ++i) {
            int col = i * 64 + (t >> 3);
            size_t src = (size_t)(n0 + col) * (NUM_IN * 2) + (size_t)kt * (BK * 2)
                       + (((t & 7) ^ ((t >> 3) & 7)) * 16);
            __builtin_amdgcn_global_load_lds((g_void_t*)(wb + src),
                (lds_void_t*)(lds + sl * SLOT + BOFF + i * 8192 + t * 16), 16, 0, 0);
        }
    };

    short8 af[4], bf0[4], bf1[4];
    auto readA4 = [&](const char* A, int kk, int mh) {
        const char* base = A + kk * 16384 + (wm * 8 + mh * 4) * 1024
                         + (kk ? la1 : la0);
        af[0] = *(const short8*)(base);
        af[1] = *(const short8*)(base + 1024);
        af[2] = *(const short8*)(base + 2048);
        af[3] = *(const short8*)(base + 3072);
    };
    auto readB4 = [&](const char* B, int co, short8* bf) {
        const char* base = B + bColB + co;
        bf[0] = *(const short8*)(base);
        bf[1] = *(const short8*)(base + 2048);
        bf[2] = *(const short8*)(base + 4096);
        bf[3] = *(const short8*)(base + 6144);
    };

    f32x4 acc[8][4] = {};
    auto mfma16 = [&](short8* bf, int mlb) {
        __builtin_amdgcn_s_setprio(1);
        #pragma unroll
        for (int mi = 0; mi < 4; ++mi)
            #pragma unroll
            for (int nf = 0; nf < 4; ++nf)
                acc[mlb + mi][nf] = __builtin_amdgcn_mfma_f32_16x16x32_bf16(
                    af[mi], bf[nf], acc[mlb + mi][nf], 0, 0, 0);
        __builtin_amdgcn_s_setprio(0);
    };

    // ---- prologue: A(0) direct; B(0),B(1) DMA; B(1) stays in flight ----
    loadA(0);                                     // vm +8
    stageB(0, 0);                                 // vm +4
    stageB(1, 1);                                 // vm +4
    asm volatile("s_waitcnt vmcnt(8)" ::: "memory");   // A(0) done
    convWriteA(0);
    asm volatile("s_waitcnt vmcnt(4)" ::: "memory");   // B(0) done, B(1) flies
    asm volatile("s_waitcnt lgkmcnt(0)" ::: "memory");
    __builtin_amdgcn_s_barrier();

    #pragma unroll 1
    for (int kt = 0; kt < NT; ++kt) {
        const int s = kt & 1;
        const char* Ap = lds + s * SLOT;
        const char* Bp = Ap + BOFF;
        const bool st1 = (kt + 1) < NT;
        const bool st2 = (kt + 2) < NT;
        // ---- phase 0: (kk0, ml0-3) ----
        if (st1) loadA(kt + 1);
        readB4(Bp, bC0, bf0);
        readA4(Ap, 0, 0);
        __builtin_amdgcn_s_barrier();
        asm volatile("s_waitcnt lgkmcnt(0)" ::: "memory");
        __builtin_amdgcn_sched_barrier(0);
        mfma16(bf0, 0);
        __builtin_amdgcn_s_barrier();
        // ---- phase 1: (kk0, ml4-7) ----
        readA4(Ap, 0, 1);
        __builtin_amdgcn_s_barrier();
        asm volatile("s_waitcnt lgkmcnt(0)" ::: "memory");
        __builtin_amdgcn_sched_barrier(0);
        mfma16(bf0, 4);
        __builtin_amdgcn_s_barrier();
        // ---- phase 2: (kk1, ml0-3) ----
        readB4(Bp, bC1, bf1);
        readA4(Ap, 1, 0);
        __builtin_amdgcn_s_barrier();
        asm volatile("s_waitcnt lgkmcnt(0)" ::: "memory");
        __builtin_amdgcn_sched_barrier(0);
        mfma16(bf1, 0);
        __builtin_amdgcn_s_barrier();
        // ---- phase 3: (kk1, ml4-7) + stage B(kt+2) + conv/write A(kt+1) ----
        if (st2) stageB(kt + 2, s);       // slot s's B: last read was ph2
        readA4(Ap, 1, 1);
        if (st1) {
            if (st2) asm volatile("s_waitcnt vmcnt(4)" ::: "memory");
            else     asm volatile("s_waitcnt vmcnt(0)" ::: "memory");
            convWriteA(s ^ 1);            // A(kt+1) -> other slot
        }
        __builtin_amdgcn_s_barrier();
        asm volatile("s_waitcnt lgkmcnt(0)" ::: "memory");
        __builtin_amdgcn_sched_barrier(0);
        mfma16(bf1, 4);
        __builtin_amdgcn_s_barrier();
    }

    // epilogue: D frag mapping col=lane&15, row=(lane>>4)*4+r
    float bj[4];
    #pragma unroll
    for (int n = 0; n < 4; ++n) bj[n] = bias[n0 + wn * 64 + n * 16 + (lane & 15)];
    const int mb = m0 + wm * 128 + (lane >> 4) * 4;
    const int nb = n0 + wn * 64 + (lane & 15);
    #pragma unroll
    for (int ml = 0; ml < 8; ++ml)
        #pragma unroll
        for (int n = 0; n < 4; ++n)
            #pragma unroll
            for (int r = 0; r < 4; ++r)
                out[(size_t)(mb + ml * 16 + r) * NUM_OUT + (nb + n * 16)] =
                    acc[ml][n][r] + bj[n];
}

extern "C" void kernel_launch(void* const* d_in, const int* in_sizes, int n_in,
                              void* d_out, int out_size, void* d_ws, size_t ws_size,
                              hipStream_t stream) {
    const float* x     = (const float*)d_in[0];
    const float* spv   = (const float*)d_in[1];
    const float* gamma = (const float*)d_in[2];
    const float* beta  = (const float*)d_in[3];
    const float* mean  = (const float*)d_in[4];
    const float* var   = (const float*)d_in[5];
    const int*   rows  = (const int*)d_in[6];
    const int*   cols  = (const int*)d_in[7];
    float* out = (float*)d_out;

    // W_t fp32 scratch lives in d_out (dead before k_gemm overwrites it).
    float* wtf = (float*)d_out;
    unsigned short* wtb = (unsigned short*)d_ws;
    float* bias = (float*)((char*)d_ws + (size_t)NUM_IN * NUM_OUT * sizeof(unsigned short));

    hipLaunchKernelGGL(k_zero, dim3((NUM_IN * NUM_OUT / 4) / 256), dim3(256), 0, stream,
                       (f32x4*)wtf);
    hipLaunchKernelGGL(k_scatter, dim3(NNZ / 256), dim3(256), 0, stream,
                       spv, rows, cols, wtf);
    hipLaunchKernelGGL(k_wprep, dim3(NUM_OUT), dim3(256), 0, stream,
                       wtf, gamma, beta, mean, var, wtb, bias);
    hipLaunchKernelGGL(k_gemm, dim3((BATCH / BM) * (NUM_OUT / BN)), dim3(512), 0, stream,
                       x, wtb, bias, out);
}